// Round 14
// baseline (84.542 us; speedup 1.0000x reference)
//
#include <hip/hip_runtime.h>
#include <hip/hip_fp16.h>

// out[s,i] = Re( U x_s ), reverse-order transposed-gate statevector sim.
// R14 = R13 (passing) with gate coefficients moved OUT of the inner loop:
//  - weights (150 f32) copied to LDS once at init;
//  - at each layer top: 15 ds_read_b64 + in-register trig builds all 10
//    transposed gates into VGPR arrays (constant-indexed after unroll);
//  - RT butterflies consume register coefficients: no DS/SMEM gate traffic,
//    no lgkmcnt mixing, ~60% fewer DS ops per wave.
// Everything else (layouts, sigma fold, SoA pack on bit 9, f16 LDS state,
// barrier-free single-wave blocks) is byte-identical to R13.

#define NQ 10
#define NL 5
#define NTH 64

typedef float f2 __attribute__((ext_vector_type(2)));
typedef unsigned int u32;

// ----- composed reversed ring-CNOT permutation (verified R3-R13), linear.
constexpr int csigma(int i) {
  for (int q = 0; q < NQ; ++q) {
    const int cb = 9 - q, tb = 9 - ((q + 1) % NQ);
    i ^= ((i >> cb) & 1) << tb;
  }
  return i;
}

// Layout-A block index (9 bits, linear, kernel {0,511}):
constexpr int cA(int s) {
  return ((s ^ (s >> 4)) & 1) | ((((s >> 1) ^ (s >> 5)) & 1) << 1) |
         ((((s >> 2) ^ (s >> 6)) & 1) << 2) |
         ((((s >> 3) ^ (s >> 7)) & 1) << 3) |
         ((((s >> 4) ^ (s >> 8)) & 1) << 4) | (((s ^ (s >> 1)) & 1) << 5) |
         ((((s >> 1) ^ (s >> 2)) & 1) << 6) |
         ((((s >> 2) ^ (s >> 3)) & 1) << 7) | (((s >> 9) & 1) << 8);
}
// Layout-C block index (linear, bijective on 9 bits):
constexpr int cC(int p) {
  return ((p >> 6) & 7) | (((p ^ (p >> 3)) & 1) << 3) |
         ((((p >> 1) ^ (p >> 4)) & 1) << 4) | (((p >> 2) & 1) << 5) |
         (((p >> 3) & 1) << 6) | (((p >> 4) & 1) << 7) | (((p >> 5) & 1) << 8);
}

// packed SoA butterfly: two independent complex bflys, component-wise.
__device__ __forceinline__ void pbfly(f2& aRe, f2& aIm, f2& bRe, f2& bIm,
                                      float h00, float h01x, float h01y,
                                      float h10x, float h10y, float h11x,
                                      float h11y) {
  const f2 naRe = h00 * aRe + h01x * bRe - h01y * bIm;
  const f2 naIm = h00 * aIm + h01x * bIm + h01y * bRe;
  const f2 nbRe = h10x * aRe - h10y * aIm + h11x * bRe - h11y * bIm;
  const f2 nbIm = h10x * aIm + h10y * aRe + h11x * bIm + h11y * bRe;
  aRe = naRe; aIm = naIm; bRe = nbRe; bIm = nbIm;
}

__device__ __forceinline__ u32 pk2(float a, float b) {
  __half2 h = __floats2half2_rn(a, b);
  return *(u32*)&h;
}
__device__ __forceinline__ f2 up2(u32 u) {
  __half2 h = *(__half2*)&u;
  return (f2){__low2float(h), __high2float(h)};
}

__global__ __launch_bounds__(NTH) void qc_apply(
    const float* __restrict__ x, const float* __restrict__ wts,
    float* __restrict__ out, int out_size) {
  __shared__ alignas(16) u32 sc[1024];     // 512 blocks x 2 words (f16x2)
  __shared__ alignas(16) float wls[NL * NQ * 3];  // raw weights, 600 B

  const int t = threadIdx.x;
  const int sv = blockIdx.x;

  // ---- stage weights into LDS once (lanes < 50; coalesced-ish 3 floats).
  if (t < NL * NQ) {
    wls[3 * t]     = wts[3 * t];
    wls[3 * t + 1] = wts[3 * t + 1];
    wls[3 * t + 2] = wts[3 * t + 2];
  }

  // ---- runtime sigma(t) and hoisted address bases (identical to R13).
  int st = t;
#pragma unroll
  for (int q = 0; q < NQ; ++q) {
    const int cb = 9 - q, tb = 9 - ((q + 1) % NQ);
    st ^= ((st >> cb) & 1) << tb;
  }
  const int baseS = cA(st) << 1;                 // sigma-read base (layout A)
  const int tb1 = t << 1;                        // RT1-write base (layout B)
  const int tb2 = (((t & 7) | ((t >> 3) << 6)) ^ ((((t >> 3) & 3)) << 3)) << 1;
  const int tc2 = cC((t & 7) | ((t >> 3) << 6)) << 1;  // RT2-write base (C)
  const int tc3 = cC(t << 3) << 1;               // RT3-read base (C)
  const int ta3 = cA(t << 3) << 1;               // RT3-write base (A)

  static constexpr int SRC[8] = {
      cA(csigma(0 << 6)) << 1, cA(csigma(1 << 6)) << 1, cA(csigma(2 << 6)) << 1,
      cA(csigma(3 << 6)) << 1, cA(csigma(4 << 6)) << 1, cA(csigma(5 << 6)) << 1,
      cA(csigma(6 << 6)) << 1, cA(csigma(7 << 6)) << 1};
#define CB1v(r) ((((r) << 6) ^ (((r) & 3) << 3)) << 1)
  static constexpr int CB1[8] = {CB1v(0), CB1v(1), CB1v(2), CB1v(3),
                                 CB1v(4), CB1v(5), CB1v(6), CB1v(7)};
  static constexpr int CC2[8] = {cC(0 << 3) << 1, cC(1 << 3) << 1,
                                 cC(2 << 3) << 1, cC(3 << 3) << 1,
                                 cC(4 << 3) << 1, cC(5 << 3) << 1,
                                 cC(6 << 3) << 1, cC(7 << 3) << 1};
  static constexpr int CC3[8] = {cC(0) << 1, cC(1) << 1, cC(2) << 1,
                                 cC(3) << 1, cC(4) << 1, cC(5) << 1,
                                 cC(6) << 1, cC(7) << 1};
  static constexpr int CWA[8] = {
      (cA(0) << 1) | 0, (cA(1) << 1) | 1, (cA(2) << 1) | 0, (cA(3) << 1) | 1,
      (cA(4) << 1) | 0, (cA(5) << 1) | 1, (cA(6) << 1) | 0, (cA(7) << 1) | 1};
  static constexpr int CAj[16] = {cA(0),  cA(1),  cA(2),  cA(3),
                                  cA(4),  cA(5),  cA(6),  cA(7),
                                  cA(8),  cA(9),  cA(10), cA(11),
                                  cA(12), cA(13), cA(14), cA(15)};

  // ---- init: x real -> layout A f16 (state s at word 2*A(s)+h(s), h=s0^s9).
  {
    const float* xs = x + (size_t)sv * 1024;
    float4 xv[4];
#pragma unroll
    for (int i4 = 0; i4 < 4; ++i4) xv[i4] = ((const float4*)xs)[4 * t + i4];
    const int ib2 = cA(16 * t) << 1;
    const int ihb = (t >> 5) & 1;  // h(16t) = s9 = t5
#pragma unroll
    for (int j = 0; j < 16; ++j) {
      const float xj = ((const float*)xv)[j];
      const int word = (ib2 ^ (CAj[j] << 1)) | (ihb ^ (j & 1));
      sc[word] = pk2(xj, 0.0f);
    }
  }

  f2 vre[8], vim[8];
  // gate coefficient registers, constant-indexed after full unroll.
  float g00[NQ], g01x[NQ], g01y[NQ], g10x[NQ], g10y[NQ], g11x[NQ], g11y[NQ];

  for (int l = NL - 1; l >= 0; --l) {
    // ---- layer-top: 30 weights from LDS -> 10 transposed gates in VGPRs.
    {
      const float* wl = wls + l * NQ * 3;
      float wb[NQ * 3];
#pragma unroll
      for (int i = 0; i < NQ * 3; ++i) wb[i] = wl[i];
#pragma unroll
      for (int q = 0; q < NQ; ++q) {
        const float th = wb[3 * q], ph = wb[3 * q + 1], lm = wb[3 * q + 2];
        const float ch_ = __cosf(0.5f * th), sh = __sinf(0.5f * th);
        g00[q] = ch_;
        g01x[q] = __cosf(ph) * sh;
        g01y[q] = __sinf(ph) * sh;
        g10x[q] = -__cosf(lm) * sh;
        g10y[q] = -__sinf(lm) * sh;
        g11x[q] = __cosf(ph + lm) * ch_;
        g11y[q] = __sinf(ph + lm) * ch_;
      }
    }

    // ======== RT1: sigma-gather (layout A); reg bits = SV bits 6-8.
#pragma unroll
    for (int r = 0; r < 8; ++r) {
      const uint2 b = *(const uint2*)&sc[baseS ^ SRC[r]];
      const f2 lo = up2(b.x);
      const f2 hi = up2(b.y);
      vre[r] = (f2){lo.x, hi.x};
      vim[r] = (f2){lo.y, hi.y};
    }
    {
      const int qb[3] = {3, 2, 1};  // reg bit e = SV bit 6+e <-> qubit 3-e
#pragma unroll
      for (int e = 0; e < 3; ++e) {
        const int q = qb[e];
        const int m = 1 << e;
#pragma unroll
        for (int r = 0; r < 8; ++r)
          if (!(r & m))
            pbfly(vre[r], vim[r], vre[r | m], vim[r | m], g00[q], g01x[q],
                  g01y[q], g10x[q], g10y[q], g11x[q], g11y[q]);
      }
    }
#pragma unroll
    for (int r = 0; r < 8; ++r) {
      uint2 b;
      b.x = pk2(vre[r].x, vre[r].y);
      b.y = pk2(vim[r].x, vim[r].y);
      *(uint2*)&sc[tb1 ^ CB1[r]] = b;
    }

    // ======== RT2 (layout B -> C); reg bits = SV bits 3-5.
#pragma unroll
    for (int r = 0; r < 8; ++r) {
      const uint2 b = *(const uint2*)&sc[tb2 ^ (r << 4)];
      vre[r] = up2(b.x);
      vim[r] = up2(b.y);
    }
    {
      const int qb[3] = {6, 5, 4};  // reg bit e = SV bit 3+e <-> qubit 6-e
#pragma unroll
      for (int e = 0; e < 3; ++e) {
        const int q = qb[e];
        const int m = 1 << e;
#pragma unroll
        for (int r = 0; r < 8; ++r)
          if (!(r & m))
            pbfly(vre[r], vim[r], vre[r | m], vim[r | m], g00[q], g01x[q],
                  g01y[q], g10x[q], g10y[q], g11x[q], g11y[q]);
      }
    }
#pragma unroll
    for (int r = 0; r < 8; ++r) {
      uint2 b;
      b.x = pk2(vre[r].x, vre[r].y);
      b.y = pk2(vim[r].x, vim[r].y);
      *(uint2*)&sc[tc2 ^ CC2[r]] = b;
    }

    // ======== RT3 (layout C); reg bits = SV bits 0-2, + bit-9 gate.
#pragma unroll
    for (int r = 0; r < 8; ++r) {
      const uint2 b = *(const uint2*)&sc[tc3 ^ CC3[r]];
      vre[r] = up2(b.x);
      vim[r] = up2(b.y);
    }
    {
      const int qb[3] = {9, 8, 7};  // reg bit e = SV bit e <-> qubit 9-e
#pragma unroll
      for (int e = 0; e < 3; ++e) {
        const int q = qb[e];
        const int m = 1 << e;
#pragma unroll
        for (int r = 0; r < 8; ++r)
          if (!(r & m))
            pbfly(vre[r], vim[r], vre[r | m], vim[r | m], g00[q], g01x[q],
                  g01y[q], g10x[q], g10y[q], g11x[q], g11y[q]);
      }
    }
    {  // qubit-0 gate on SV bit 9 = pack halves (.x <-> .y), scalar form.
      const float h00 = g00[0], h01x = g01x[0], h01y = g01y[0],
                  h10x = g10x[0], h10y = g10y[0], h11x = g11x[0],
                  h11y = g11y[0];
#pragma unroll
      for (int r = 0; r < 8; ++r) {
        const float re0 = vre[r].x, im0 = vim[r].x;
        const float re1 = vre[r].y, im1 = vim[r].y;
        vre[r].x = h00 * re0 + h01x * re1 - h01y * im1;
        vim[r].x = h00 * im0 + h01x * im1 + h01y * re1;
        vre[r].y = h10x * re0 - h10y * im0 + h11x * re1 - h11y * im1;
        vim[r].y = h10x * im0 + h10y * re0 + h11x * im1 + h11y * re1;
      }
    }
    if (l != 0) {
#pragma unroll
      for (int r = 0; r < 8; ++r) {
        const int w0 = ta3 ^ CWA[r];
        sc[w0] = pk2(vre[r].x, vim[r].x);
        sc[w0 ^ 513] = pk2(vre[r].y, vim[r].y);
      }
    }
  }

  // ---- output: reals only. .x -> indices 8t..8t+7, .y -> +512.
  const size_t ob = (size_t)sv * 1024 + 8 * t;
  if (ob + 8 <= (size_t)out_size) {
    *(float4*)(out + ob) = make_float4(vre[0].x, vre[1].x, vre[2].x, vre[3].x);
    *(float4*)(out + ob + 4) =
        make_float4(vre[4].x, vre[5].x, vre[6].x, vre[7].x);
  }
  if (ob + 512 + 8 <= (size_t)out_size) {
    *(float4*)(out + ob + 512) =
        make_float4(vre[0].y, vre[1].y, vre[2].y, vre[3].y);
    *(float4*)(out + ob + 516) =
        make_float4(vre[4].y, vre[5].y, vre[6].y, vre[7].y);
  }
}

extern "C" void kernel_launch(void* const* d_in, const int* in_sizes, int n_in,
                              void* d_out, int out_size, void* d_ws, size_t ws_size,
                              hipStream_t stream) {
  const float* x = (const float*)d_in[0];   // [128,16,32,32] f32
  const float* w = (const float*)d_in[1];   // [5,10,3] f32
  float* out = (float*)d_out;               // f32 (real part of complex64)
  const int nstates = in_sizes[0] / 1024;   // 2048
  qc_apply<<<nstates, NTH, 0, stream>>>(x, w, out, out_size);
}

// Round 15
// 81.016 us; speedup vs baseline: 1.0435x; 1.0435x over previous
//
#include <hip/hip_runtime.h>

// out[s,i] = Re( U x_s ), reverse-order transposed-gate statevector sim.
// R15: 2 statevectors packed per f2 lane (SoA), R9's VERIFIED index maps.
// 128-thr block (2 waves) handles SVs (2b, 2b+1); 8 states/thread/SV.
// Every LDS slot = float4(reA, imA, reB, imB) -> all state traffic b128;
// gates read as 2x b128 (was 7x b32) -> ~5x less LDS-pipe occupancy.
// Per reversed layer (qubit q <-> bit 9-q; sigma = composed ring-CNOT):
//   A: regs = bits 7-9 (q=2,1,0), sigma folded into gather reads
//   B: regs = bits 3,5,6 (q=6,4,3)
//   C: regs = bits 0-2 (q=9,8,7); then q=5 (SV bit 4 = lane bit 1) via
//      __shfl_xor(.,2); layer-0 streams registers -> global (reals).
// Slot swizzle swz(k)=k^((((k>>4)^(k>>7))&7)<<1) (R9-verified).

#define NQ 10
#define NL 5
#define NTH 128

typedef float f2 __attribute__((ext_vector_type(2)));

// Composed reversed-CNOT permutation (temporal chain, q=0 step first).
// Verified rounds 3-13. GF(2)-linear.
constexpr int csigma(int i) {
  for (int q = 0; q < NQ; ++q) {
    const int cb = 9 - q, tb = 9 - ((q + 1) % NQ);
    i ^= ((i >> cb) & 1) << tb;
  }
  return i;
}

__device__ __forceinline__ int swz(int k) {
  return k ^ ((((k >> 4) ^ (k >> 7)) & 7) << 1);
}

// SoA packed butterfly: two independent complex bflys (one per SV).
__device__ __forceinline__ void pbfly(f2& aRe, f2& aIm, f2& bRe, f2& bIm,
                                      float h00, float h01x, float h01y,
                                      float h10x, float h10y, float h11x,
                                      float h11y) {
  const f2 naRe = h00 * aRe + h01x * bRe - h01y * bIm;
  const f2 naIm = h00 * aIm + h01x * bIm + h01y * bRe;
  const f2 nbRe = h10x * aRe - h10y * aIm + h11x * bRe - h11y * bIm;
  const f2 nbIm = h10x * aIm + h10y * aRe + h11x * bIm + h11y * bRe;
  aRe = naRe; aIm = naIm; bRe = nbRe; bIm = nbIm;
}

#define LOAD_G4(G)                                                    \
  const float4 GA = *(const float4*)(G);                              \
  const float4 GB = *(const float4*)((G) + 4);                        \
  const float h00 = GA.x, h01x = GA.z, h01y = GA.w;                   \
  const float h10x = GB.x, h10y = GB.y, h11x = GB.z, h11y = GB.w;

__global__ __launch_bounds__(NTH) void qc_apply(
    const float* __restrict__ x, const float* __restrict__ wts,
    float* __restrict__ out, int out_size) {
  __shared__ alignas(16) float4 sc[1024];        // 16 KB state (2 SVs)
  __shared__ alignas(16) float sg[NL * NQ * 8];  // transposed gates

  const int t = threadIdx.x;                 // 7 bits
  const int sv0 = blockIdx.x * 2;
  const int mT = (((t >> 1) ^ (t >> 4)) & 7) << 1;  // swz mask for k=8t+j

  // ---- in-kernel gate build (lanes < 50): transposed U3, h00 real.
  if (t < NL * NQ) {
    const float th = wts[3 * t], ph = wts[3 * t + 1], lm = wts[3 * t + 2];
    const float ch_ = __cosf(0.5f * th), sh = __sinf(0.5f * th);
    float* G = sg + t * 8;
    G[0] = ch_;                 G[1] = 0.0f;
    G[2] = __cosf(ph) * sh;     G[3] = __sinf(ph) * sh;
    G[4] = -__cosf(lm) * sh;    G[5] = -__sinf(lm) * sh;
    G[6] = __cosf(ph + lm) * ch_; G[7] = __sinf(ph + lm) * ch_;
  }

  // ---- init: state k of SV a/b -> slot (8t+j)^mT = swz(8t+j), imag 0.
  {
    const float* xa = x + (size_t)sv0 * 1024;
    const float* xb = xa + 1024;
    const float4 a0 = ((const float4*)xa)[2 * t];
    const float4 a1 = ((const float4*)xa)[2 * t + 1];
    const float4 b0 = ((const float4*)xb)[2 * t];
    const float4 b1 = ((const float4*)xb)[2 * t + 1];
    const float va[8] = {a0.x, a0.y, a0.z, a0.w, a1.x, a1.y, a1.z, a1.w};
    const float vb[8] = {b0.x, b0.y, b0.z, b0.w, b1.x, b1.y, b1.z, b1.w};
#pragma unroll
    for (int j = 0; j < 8; ++j)
      sc[(8 * t + j) ^ mT] = make_float4(va[j], 0.f, vb[j], 0.f);
  }
  __syncthreads();

  // sigma: runtime image of the 7 thread bits + constexpr images of bits 7-9.
  int sL = t;
#pragma unroll
  for (int q = 0; q < NQ; ++q) {
    const int cb = 9 - q, tb = 9 - ((q + 1) % NQ);
    sL ^= ((sL >> cb) & 1) << tb;
  }
  constexpr int SH7 = csigma(1 << 7), SH8 = csigma(1 << 8),
                SH9 = csigma(1 << 9);

  f2 vre[8], vim[8];

#pragma unroll 1
  for (int l = NL - 1; l >= 0; --l) {
    const float* gl = sg + l * NQ * 8;

    // ======== pass A: sigma gather; regs = bits 7-9, thread = bits 0-6.
#pragma unroll
    for (int r = 0; r < 8; ++r) {
      const int idx = sL ^ ((r & 1) ? SH7 : 0) ^ ((r & 2) ? SH8 : 0) ^
                      ((r & 4) ? SH9 : 0);
      const float4 s = sc[swz(idx)];
      vre[r] = (f2){s.x, s.z};
      vim[r] = (f2){s.y, s.w};
    }
#pragma unroll
    for (int e = 0; e < 3; ++e) {   // reg bit e = SV bit 7+e <-> qubit 2-e
      LOAD_G4(gl + (2 - e) * 8)
      const int m = 1 << e;
#pragma unroll
      for (int r = 0; r < 8; ++r)
        if (!(r & m))
          pbfly(vre[r], vim[r], vre[r | m], vim[r | m], h00, h01x, h01y,
                h10x, h10y, h11x, h11y);
    }
    __syncthreads();  // all gathers done before layout change
#pragma unroll
    for (int r = 0; r < 8; ++r)
      sc[swz((r << 7) | t)] =
          make_float4(vre[r].x, vim[r].x, vre[r].y, vim[r].y);
    __syncthreads();

    // ======== pass B: regs = bits 3,5,6; thread = bits 0-2,4,7-9.
    const int bbase = (t & 7) | (((t >> 3) & 1) << 4) | ((t >> 4) << 7);
#pragma unroll
    for (int r = 0; r < 8; ++r) {
      const int idx = bbase | ((r & 1) << 3) | (((r >> 1) & 1) << 5) |
                      (((r >> 2) & 1) << 6);
      const float4 s = sc[swz(idx)];
      vre[r] = (f2){s.x, s.z};
      vim[r] = (f2){s.y, s.w};
    }
    {
      const int GQ[3] = {6, 4, 3};  // reg bits 0,1,2 = SV bits 3,5,6
#pragma unroll
      for (int e = 0; e < 3; ++e) {
        LOAD_G4(gl + GQ[e] * 8)
        const int m = 1 << e;
#pragma unroll
        for (int r = 0; r < 8; ++r)
          if (!(r & m))
            pbfly(vre[r], vim[r], vre[r | m], vim[r | m], h00, h01x, h01y,
                  h10x, h10y, h11x, h11y);
      }
    }
#pragma unroll
    for (int r = 0; r < 8; ++r) {
      const int idx = bbase | ((r & 1) << 3) | (((r >> 1) & 1) << 5) |
                      (((r >> 2) & 1) << 6);
      sc[swz(idx)] = make_float4(vre[r].x, vim[r].x, vre[r].y, vim[r].y);
    }
    __syncthreads();

    // ======== pass C: regs = bits 0-2 (slots (8t+j)^mT); thread = bits 3-9.
#pragma unroll
    for (int j = 0; j < 8; ++j) {
      const float4 s = sc[(8 * t + j) ^ mT];
      vre[j] = (f2){s.x, s.z};
      vim[j] = (f2){s.y, s.w};
    }
#pragma unroll
    for (int e = 0; e < 3; ++e) {   // reg bit e = SV bit e <-> qubit 9-e
      LOAD_G4(gl + (9 - e) * 8)
      const int m = 1 << e;
#pragma unroll
      for (int r = 0; r < 8; ++r)
        if (!(r & m))
          pbfly(vre[r], vim[r], vre[r | m], vim[r | m], h00, h01x, h01y,
                h10x, h10y, h11x, h11y);
    }
    // q=5 gate on SV bit 4 = thread bit 1: __shfl_xor mask 2 (intra-quad).
    {
      LOAD_G4(gl + 5 * 8)
      const bool hi = (t >> 1) & 1;
      const float c1 = hi ? h11x : h00;
      const float c2 = hi ? h11y : 0.0f;
      const float c3 = hi ? h10x : h01x;
      const float c4 = hi ? h10y : h01y;
#pragma unroll
      for (int r = 0; r < 8; ++r) {
        f2 pRe, pIm;
        pRe.x = __shfl_xor(vre[r].x, 2);
        pRe.y = __shfl_xor(vre[r].y, 2);
        pIm.x = __shfl_xor(vim[r].x, 2);
        pIm.y = __shfl_xor(vim[r].y, 2);
        const f2 nRe = c1 * vre[r] - c2 * vim[r] + c3 * pRe - c4 * pIm;
        const f2 nIm = c1 * vim[r] + c2 * vre[r] + c3 * pIm + c4 * pRe;
        vre[r] = nRe;
        vim[r] = nIm;
      }
    }
    if (l != 0) {
#pragma unroll
      for (int j = 0; j < 8; ++j)
        sc[(8 * t + j) ^ mT] =
            make_float4(vre[j].x, vim[j].x, vre[j].y, vim[j].y);
      __syncthreads();
    }
  }

  // ---- output: reals only; thread holds states 8t..8t+7 of both SVs.
  const size_t ob = (size_t)sv0 * 1024 + 8 * t;
  if (ob + 8 <= (size_t)out_size) {
    *(float4*)(out + ob) = make_float4(vre[0].x, vre[1].x, vre[2].x, vre[3].x);
    *(float4*)(out + ob + 4) =
        make_float4(vre[4].x, vre[5].x, vre[6].x, vre[7].x);
  }
  const size_t ob1 = ob + 1024;
  if (ob1 + 8 <= (size_t)out_size) {
    *(float4*)(out + ob1) =
        make_float4(vre[0].y, vre[1].y, vre[2].y, vre[3].y);
    *(float4*)(out + ob1 + 4) =
        make_float4(vre[4].y, vre[5].y, vre[6].y, vre[7].y);
  }
}

extern "C" void kernel_launch(void* const* d_in, const int* in_sizes, int n_in,
                              void* d_out, int out_size, void* d_ws, size_t ws_size,
                              hipStream_t stream) {
  const float* x = (const float*)d_in[0];   // [128,16,32,32] f32
  const float* w = (const float*)d_in[1];   // [5,10,3] f32
  float* out = (float*)d_out;               // f32 (real part of complex64)
  const int nstates = in_sizes[0] / 1024;   // 2048
  qc_apply<<<nstates / 2, NTH, 0, stream>>>(x, w, out, out_size);
}